// Round 16
// baseline (454.400 us; speedup 1.0000x reference)
//
#include <hip/hip_runtime.h>
#include <math.h>

// ---------------------------------------------------------------------------
// SimpleGNN (4-layer GCN + mean pool + sigmoid) on MI355X.
//   - CSR build: atomic-free bucket sort (R6), NCH=128.
//   - R15 consolidation kept (hist+wconv fused, xscale in bucket_csr,
//     binary-search pool).
//   - R16: COLUMN-SLICED aggregation. fp8 gather buffer stored slice-major
//     (4 slices x 32 cols = 3.2MB/slice, fits every XCD's 4MB L2 by
//     replication). agg runs as 4 sequential slice kernels: 8 lanes/row x
//     dword = 8 edges/gather-instr, gathers are L2 hits after warm-up.
//     Tests the L3-path-ceiling hypothesis (agg128 fetched 88MB @ 1.77TB/s).
//   - h in BF16; layers 2,3 = bf16 MFMA GEMM (16x16x32, MB=128).
//   - norm factored into GEMM epilogue; aggregation = pure gather-sum.
// ---------------------------------------------------------------------------

typedef float f32x2 __attribute__((ext_vector_type(2)));
typedef float f32x4 __attribute__((ext_vector_type(4)));
typedef short bf16x8 __attribute__((ext_vector_type(8)));   // 8 bf16 = 4 VGPRs

#define BKT    64     // nodes per bucket (shift 6)
#define NCH    128    // edge chunks
#define MAXBUK 2048   // LDS bucket counters (nbuk = 1563 @ n=100k)
#define DCAP   2048   // per-bucket LDS colarr staging
#define WTP    136    // padded row length of transposed W (bf16)

// round-to-nearest-even f32 -> bf16
__device__ __forceinline__ unsigned short f2bf(float f) {
    unsigned u = __float_as_uint(f);
    return (unsigned short)((u + 0x7fffu + ((u >> 16) & 1u)) >> 16);
}
__device__ __forceinline__ float bf2f(unsigned short b) {
    return __uint_as_float((unsigned)b << 16);
}

// ---- CSR pass A + weight prep fused: blocks [0,NCH) hist, [NCH,NCH+128) wconv ----
__global__ __launch_bounds__(256) void hist_wconv(const int* __restrict__ dst,
                                                  int* __restrict__ hmatT,
                                                  int e, int nbuk,
                                                  const float* __restrict__ W2,
                                                  unsigned short* __restrict__ wtg2,
                                                  const float* __restrict__ W3,
                                                  unsigned short* __restrict__ wtg3) {
    if (blockIdx.x >= NCH) {
        int gid = (blockIdx.x - NCH) * 256 + threadIdx.x;   // [0, 32768)
        const float* W = (gid < 128 * 128) ? W2 : W3;
        unsigned short* wtg = (gid < 128 * 128) ? wtg2 : wtg3;
        int idx = gid & (128 * 128 - 1);
        int k = idx >> 7, c = idx & 127;
        wtg[c * WTP + k] = f2bf(W[idx]);
        return;
    }
    __shared__ int h[MAXBUK];
    for (int i = threadIdx.x; i < nbuk; i += 256) h[i] = 0;
    __syncthreads();
    const int per = (e + NCH - 1) / NCH;
    const int beg = blockIdx.x * per;
    const int end = min(beg + per, e);
    for (int i = beg + threadIdx.x; i < end; i += 256)
        atomicAdd(&h[dst[i] >> 6], 1);          // LDS atomic
    __syncthreads();
    for (int b = threadIdx.x; b < nbuk; b += 256)
        hmatT[b * NCH + blockIdx.x] = h[b];
}

// ---- CSR pass B1: per-bucket exclusive scan over its NCH chunk-counts ----
__global__ __launch_bounds__(256) void scan_chunks(int* __restrict__ hmatT,
                                                   int* __restrict__ totals, int nbuk) {
    int b = blockIdx.x * 4 + (threadIdx.x >> 6);
    if (b >= nbuk) return;
    const int lane = threadIdx.x & 63;
    int* row = hmatT + b * NCH;
    int carry = 0;
    #pragma unroll
    for (int q = 0; q < NCH / 64; ++q) {
        int v = row[q * 64 + lane];
        int x = v;
        #pragma unroll
        for (int off = 1; off < 64; off <<= 1) {
            int y = __shfl_up(x, off);
            if (lane >= off) x += y;
        }
        row[q * 64 + lane] = x - v + carry;
        carry += __shfl(x, 63);
    }
    if (lane == 0) totals[b] = carry;
}

// ---- CSR pass B2: single-block chunked exclusive scan ----
__global__ void scan_kernel(const int* __restrict__ counts, int* __restrict__ rowptr, int n) {
    __shared__ int wsum[16];
    __shared__ int carry_s;
    const int tid  = threadIdx.x;            // 1024 threads
    const int lane = tid & 63, wid = tid >> 6;
    if (tid == 0) carry_s = 0;
    __syncthreads();
    const int nchunk = (n + 4095) >> 12;
    for (int c = 0; c < nchunk; ++c) {
        int i0 = (c << 12) + tid * 4;
        int4 v = make_int4(0, 0, 0, 0);
        if (i0 + 3 < n) {
            v = *(const int4*)(counts + i0);
        } else {
            if (i0     < n) v.x = counts[i0];
            if (i0 + 1 < n) v.y = counts[i0 + 1];
            if (i0 + 2 < n) v.z = counts[i0 + 2];
            if (i0 + 3 < n) v.w = counts[i0 + 3];
        }
        int s1 = v.x, s2 = s1 + v.y, s3 = s2 + v.z, s4 = s3 + v.w;
        int x = s4;
        #pragma unroll
        for (int off = 1; off < 64; off <<= 1) {
            int y = __shfl_up(x, off);
            if (lane >= off) x += y;
        }
        if (lane == 63) wsum[wid] = x;
        __syncthreads();
        if (wid == 0) {
            int s = (lane < 16) ? wsum[lane] : 0;
            #pragma unroll
            for (int off = 1; off < 16; off <<= 1) {
                int y = __shfl_up(s, off);
                if (lane >= off) s += y;
            }
            if (lane < 16) wsum[lane] = s;
        }
        __syncthreads();
        int carry = carry_s + ((wid > 0) ? wsum[wid - 1] : 0);
        int excl  = carry + x - s4;
        if (i0     < n) rowptr[i0 + 1] = excl + s1;
        if (i0 + 1 < n) rowptr[i0 + 2] = excl + s2;
        if (i0 + 2 < n) rowptr[i0 + 3] = excl + s3;
        if (i0 + 3 < n) rowptr[i0 + 4] = excl + s4;
        __syncthreads();
        if (tid == 1023) carry_s = carry + x;
        __syncthreads();
    }
    if (tid == 0) rowptr[0] = 0;
}

// ---- CSR pass C: partition edges into bucket-grouped order ----
__global__ __launch_bounds__(256) void partition_kernel(const int* __restrict__ src,
                                                        const int* __restrict__ dst,
                                                        const int* __restrict__ hmatT,
                                                        const int* __restrict__ bukBase,
                                                        int* __restrict__ part,
                                                        int e, int nbuk) {
    __shared__ int cur[MAXBUK];
    for (int b = threadIdx.x; b < nbuk; b += 256)
        cur[b] = bukBase[b] + hmatT[b * NCH + blockIdx.x];
    __syncthreads();
    const int per = (e + NCH - 1) / NCH;
    const int beg = blockIdx.x * per;
    const int end = min(beg + per, e);
    for (int i = beg + threadIdx.x; i < end; i += 256) {
        int d = dst[i], s = src[i];
        int pos = atomicAdd(&cur[d >> 6], 1);   // LDS atomic
        part[pos] = (d & 63) | (s << 6);        // s < 2^17 -> fits
    }
}

// ---- CSR pass D: per-bucket local CSR finish + fused dinv + fused xscale ----
__global__ __launch_bounds__(256) void bucket_csr(const int* __restrict__ part,
                                                  const int* __restrict__ bukBase,
                                                  int* __restrict__ colarr,
                                                  int* __restrict__ rowptr,
                                                  float* __restrict__ dinv,
                                                  const float* __restrict__ x,
                                                  float* __restrict__ xs,
                                                  int n, int e) {
    __shared__ int hist[BKT];
    __shared__ int cursor[BKT];
    __shared__ float dls[BKT];
    __shared__ int loc[DCAP];
    const int b = blockIdx.x;
    const int ebeg = bukBase[b], eend = bukBase[b + 1];
    if (threadIdx.x < BKT) hist[threadIdx.x] = 0;
    __syncthreads();
    for (int i = ebeg + threadIdx.x; i < eend; i += 256)
        atomicAdd(&hist[part[i] & (BKT - 1)], 1);
    __syncthreads();
    if (threadIdx.x < 64) {
        const int lane = threadIdx.x;
        int c = hist[lane];
        int x0 = c;
        #pragma unroll
        for (int off = 1; off < 64; off <<= 1) { int y = __shfl_up(x0, off); if (lane >= off) x0 += y; }
        int excl = x0 - c;
        cursor[lane] = excl;
        float dv = rsqrtf((float)c + 1.0f);
        dls[lane] = dv;
        int node = b * BKT + lane;
        if (node < n) {
            rowptr[node] = ebeg + excl;
            dinv[node]   = dv;
        }
    }
    if (b == 0 && threadIdx.x == 0) rowptr[n] = e;
    __syncthreads();
    for (int i = ebeg + threadIdx.x; i < eend; i += 256) {
        int p = part[i];
        int pos = atomicAdd(&cursor[p & (BKT - 1)], 1);  // LDS atomic
        int s = p >> 6;
        if (pos < DCAP) loc[pos] = s;
        else colarr[ebeg + pos] = s;   // statistically unreachable overflow path
    }
    __syncthreads();
    const int cnt = min(eend - ebeg, DCAP);
    for (int i = threadIdx.x; i < cnt; i += 256) colarr[ebeg + i] = loc[i];
    // fused xscale: xs[node,c] = x[node,c] * dinv[node] for this bucket's nodes
    for (int i = threadIdx.x; i < BKT * 6; i += 256) {
        int node = b * BKT + i / 6;
        if (node < n) {
            int idx = node * 6 + (i % 6);
            xs[idx] = x[idx] * dls[i / 6];
        }
    }
}

// ax[i] = dinv[i] * ( sum_{s in N(i)} xs[s] + xs[i] )    (6-dim)
__global__ void aggx_kernel(const float* __restrict__ xs, const int* __restrict__ rowptr,
                            const int* __restrict__ colarr, const float* __restrict__ dinv,
                            float* __restrict__ ax, int n) {
    int i = blockIdx.x * 256 + threadIdx.x;
    if (i >= n) return;
    float a0 = 0, a1 = 0, a2 = 0, a3 = 0, a4 = 0, a5 = 0;
    int beg = rowptr[i], end = rowptr[i + 1];
    for (int e = beg; e < end; ++e) {
        int s = colarr[e];
        const float* xr = xs + (size_t)s * 6;
        a0 += xr[0]; a1 += xr[1]; a2 += xr[2];
        a3 += xr[3]; a4 += xr[4]; a5 += xr[5];
    }
    const float* xi = xs + (size_t)i * 6;
    float di = dinv[i];
    float* o = ax + (size_t)i * 6;
    o[0] = (a0 + xi[0]) * di;
    o[1] = (a1 + xi[1]) * di;
    o[2] = (a2 + xi[2]) * di;
    o[3] = (a3 + xi[3]) * di;
    o[4] = (a4 + xi[4]) * di;
    o[5] = (a5 + xi[5]) * di;
}

// h1 = bf16( relu(ax @ W1 + b1) )   (6 -> 128); thread = one (node, col)
__global__ __launch_bounds__(256) void gemm1_kernel(const float* __restrict__ ax,
                                                    const float* __restrict__ W1,
                                                    const float* __restrict__ b1,
                                                    unsigned short* __restrict__ h1, int n) {
    __shared__ float Wl[6 * 128];
    __shared__ float bl[128];
    for (int i = threadIdx.x; i < 6 * 128; i += 256) Wl[i] = W1[i];
    if (threadIdx.x < 128) bl[threadIdx.x] = b1[threadIdx.x];
    __syncthreads();
    int gid = blockIdx.x * 256 + threadIdx.x;
    int node = gid >> 7, c = gid & 127;
    if (node >= n) return;
    const float* ar = ax + (size_t)node * 6;
    float acc = bl[c];
    #pragma unroll
    for (int k = 0; k < 6; ++k) acc += ar[k] * Wl[k * 128 + c];
    h1[(size_t)node * 128 + c] = f2bf(fmaxf(acc, 0.0f));
}

// gout (SLICE-MAJOR fp8): slice s holds dwords [s*n*8 , (s+1)*n*8), node row = 8 dwords (32B)
// gout[s*n*8 + node*8 + dw] covers fp8 cols s*32 + dw*4 .. +3
#define MB 128  // nodes per block (2 halves amortize Wt staging)
__global__ __launch_bounds__(256) void gemm128_mfma(const unsigned short* __restrict__ hb,
                                                    const unsigned short* __restrict__ wtg,
                                                    const float* __restrict__ dinv,
                                                    int* __restrict__ gout, int n) {
    __shared__ unsigned short Wt[128 * WTP];   // 34.8 KB, transposed W
    __shared__ float dl[MB];
    __shared__ float ctile[4][16][16];         // per-wave epilogue repack
    const int tid = threadIdx.x;
    const int node0 = blockIdx.x * MB;
    {   // stage Wt: straight 16B copies (wtg already transposed+padded)
        const int4* s4 = (const int4*)wtg;
        int4* d4 = (int4*)Wt;
        for (int i = tid; i < 128 * WTP * 2 / 16; i += 256) d4[i] = s4[i];
    }
    if (tid < MB) {
        int node = node0 + tid;
        dl[tid] = (node < n) ? dinv[node] : 0.f;
    }
    __syncthreads();
    const int wid  = tid >> 6, lane = tid & 63;
    const int ccol = lane & 15;
    const int koff = (lane >> 4) * 8;           // k-chunk within 32
    float* ct = &ctile[wid][0][0];
    #pragma unroll
    for (int half = 0; half < 2; ++half) {
        const int wn0  = node0 + half * 64 + wid * 16;   // this wave's 16 nodes
        const int arow = wn0 + (lane & 15);              // A row (hb has slack)
        bf16x8 a0 = *(const bf16x8*)(hb + (size_t)arow * 128 +  0 + koff);
        bf16x8 a1 = *(const bf16x8*)(hb + (size_t)arow * 128 + 32 + koff);
        bf16x8 a2 = *(const bf16x8*)(hb + (size_t)arow * 128 + 64 + koff);
        bf16x8 a3 = *(const bf16x8*)(hb + (size_t)arow * 128 + 96 + koff);
        #pragma unroll
        for (int nt = 0; nt < 8; ++nt) {            // 16-col output tiles
            const unsigned short* wb = Wt + (size_t)(nt * 16 + (lane & 15)) * WTP + koff;
            f32x4 c = {0.f, 0.f, 0.f, 0.f};
            c = __builtin_amdgcn_mfma_f32_16x16x32_bf16(a0, *(const bf16x8*)(wb +  0), c, 0, 0, 0);
            c = __builtin_amdgcn_mfma_f32_16x16x32_bf16(a1, *(const bf16x8*)(wb + 32), c, 0, 0, 0);
            c = __builtin_amdgcn_mfma_f32_16x16x32_bf16(a2, *(const bf16x8*)(wb + 64), c, 0, 0, 0);
            c = __builtin_amdgcn_mfma_f32_16x16x32_bf16(a3, *(const bf16x8*)(wb + 96), c, 0, 0, 0);
            #pragma unroll
            for (int r = 0; r < 4; ++r) {
                int row = (lane >> 4) * 4 + r;
                ct[row * 16 + ccol] = c[r] * dl[half * 64 + wid * 16 + row];
            }
            int rrow = lane >> 2, rdw = lane & 3;
            f32x4 v = *(const f32x4*)&ct[rrow * 16 + rdw * 4];
            int w = __builtin_amdgcn_cvt_pk_fp8_f32(v[0], v[1], 0, false);
            w     = __builtin_amdgcn_cvt_pk_fp8_f32(v[2], v[3], w, true);
            int onode = wn0 + rrow;
            int dwi = nt * 4 + rdw;             // 0..31 dword index in full row
            int sl = dwi >> 3, dw = dwi & 7;    // slice, dword-in-slice
            if (onode < n)
                gout[(size_t)sl * n * 8 + (size_t)onode * 8 + dw] = w;
        }
    }
}

// One 32-col slice of: out = bf16( relu_opt( dinv*( sum g[s] + g[node] ) + b ) )
// Slice buffer = 3.2MB -> L2-resident per XCD. 8 lanes/row x dword = 8 edges
// per gather instruction; 16 edges/iter main + masked 16-edge tail.
__global__ __launch_bounds__(256) void agg128_slice(const int* __restrict__ g,
                                                    const int* __restrict__ rowptr,
                                                    const int* __restrict__ colarr,
                                                    const float* __restrict__ dinv,
                                                    const float* __restrict__ bias,
                                                    unsigned short* __restrict__ out,
                                                    int n, int relu, int slice) {
    int node = blockIdx.x * 4 + (threadIdx.x >> 6);
    if (node >= n) return;
    const int lane = threadIdx.x & 63;
    const int eg = lane >> 3;          // edge group 0..7
    const int c  = lane & 7;           // dword within 32B slice row
    const int* gs = g + (size_t)slice * n * 8;
    const int beg = rowptr[node], end = rowptr[node + 1];
    f32x2 a0 = {0.f, 0.f}, a1 = {0.f, 0.f};
    const f32x2 z = {0.f, 0.f};
    int e = beg;
    // main: 16 edges/iter (2 gathers in flight, 8 edges each)
    for (; e + 16 <= end; e += 16) {
        int s0 = colarr[e     + eg];
        int s1 = colarr[e + 8 + eg];
        int w0 = gs[(size_t)s0 * 8 + c];
        int w1 = gs[(size_t)s1 * 8 + c];
        a0 += __builtin_amdgcn_cvt_pk_f32_fp8(w0, false);
        a1 += __builtin_amdgcn_cvt_pk_f32_fp8(w0, true);
        a0 += __builtin_amdgcn_cvt_pk_f32_fp8(w1, false);
        a1 += __builtin_amdgcn_cvt_pk_f32_fp8(w1, true);
    }
    // tail: single masked 16-edge block
    if (e < end) {
        int i0 = e + eg, i1 = e + 8 + eg;
        bool m0 = i0 < end, m1 = i1 < end;
        int s0 = m0 ? colarr[i0] : node;   // node's row always valid
        int s1 = m1 ? colarr[i1] : node;
        int w0 = gs[(size_t)s0 * 8 + c];
        int w1 = gs[(size_t)s1 * 8 + c];
        a0 += (m0 ? __builtin_amdgcn_cvt_pk_f32_fp8(w0, false) : z);
        a1 += (m0 ? __builtin_amdgcn_cvt_pk_f32_fp8(w0, true)  : z);
        a0 += (m1 ? __builtin_amdgcn_cvt_pk_f32_fp8(w1, false) : z);
        a1 += (m1 ? __builtin_amdgcn_cvt_pk_f32_fp8(w1, true)  : z);
    }
    // reduce across the 8 edge groups (lanes with equal c)
    #pragma unroll
    for (int off = 8; off <= 32; off <<= 1) {
        a0[0] += __shfl_xor(a0[0], off); a0[1] += __shfl_xor(a0[1], off);
        a1[0] += __shfl_xor(a1[0], off); a1[1] += __shfl_xor(a1[1], off);
    }
    if (eg == 0) {
        int wsv = gs[(size_t)node * 8 + c];
        f32x2 slo = __builtin_amdgcn_cvt_pk_f32_fp8(wsv, false);
        f32x2 shi = __builtin_amdgcn_cvt_pk_f32_fp8(wsv, true);
        float di = dinv[node];
        float4 b = *(const float4*)(bias + slice * 32 + c * 4);
        float o0 = (a0[0] + slo[0]) * di + b.x;
        float o1 = (a0[1] + slo[1]) * di + b.y;
        float o2 = (a1[0] + shi[0]) * di + b.z;
        float o3 = (a1[1] + shi[1]) * di + b.w;
        if (relu) {
            o0 = fmaxf(o0, 0.f); o1 = fmaxf(o1, 0.f);
            o2 = fmaxf(o2, 0.f); o3 = fmaxf(o3, 0.f);
        }
        ushort4 o;
        o.x = f2bf(o0); o.y = f2bf(o1); o.z = f2bf(o2); o.w = f2bf(o3);
        *(ushort4*)(out + (size_t)node * 128 + slice * 32 + c * 4) = o;
    }
}

// t[i] = dot(hb[i,:], W4[:,0]) * dinv[i]   (hb bf16)
__global__ void head_kernel(const unsigned short* __restrict__ hb,
                            const float* __restrict__ W4,
                            const float* __restrict__ dinv, float* __restrict__ t, int n) {
    int node = blockIdx.x * 4 + (threadIdx.x >> 6);
    if (node >= n) return;
    int lane = threadIdx.x & 63;
    ushort2 v = ((const ushort2*)(hb + (size_t)node * 128))[lane];
    float2 w = ((const float2*)W4)[lane];
    float p = bf2f(v.x) * w.x + bf2f(v.y) * w.y;
    #pragma unroll
    for (int off = 32; off; off >>= 1) p += __shfl_xor(p, off);
    if (lane == 0) t[node] = p * dinv[node];
}

// s[i] = dinv[i]*( sum t[s] + t[i] ) + b4
__global__ void aggs_kernel(const float* __restrict__ t, const int* __restrict__ rowptr,
                            const int* __restrict__ colarr, const float* __restrict__ dinv,
                            const float* __restrict__ b4, float* __restrict__ s, int n) {
    int i = blockIdx.x * 256 + threadIdx.x;
    if (i >= n) return;
    float acc = 0.f;
    int beg = rowptr[i], end = rowptr[i + 1];
    int e = beg;
    for (; e + 3 < end; e += 4) {
        acc += (t[colarr[e]] + t[colarr[e + 1]]) + (t[colarr[e + 2]] + t[colarr[e + 3]]);
    }
    for (; e < end; ++e) acc += t[colarr[e]];
    s[i] = (acc + t[i]) * dinv[i] + b4[0];
}

// one wave per graph: binary-search the sorted batch for this graph's range,
// then mean + sigmoid straight to d_out.
__global__ void pool_kernel(const float* __restrict__ sv, const int* __restrict__ batch,
                            float* __restrict__ out, int n, int ng) {
    int g = blockIdx.x * 4 + (threadIdx.x >> 6);
    if (g >= ng) return;
    int lane = threadIdx.x & 63;
    int lo = 0, hi = n;
    while (lo < hi) { int mid = (lo + hi) >> 1; if (batch[mid] < g) lo = mid + 1; else hi = mid; }
    int beg = lo;
    hi = n;
    while (lo < hi) { int mid = (lo + hi) >> 1; if (batch[mid] < g + 1) lo = mid + 1; else hi = mid; }
    int end = lo;
    float acc = 0.f;
    for (int i = beg + lane; i < end; i += 64) acc += sv[i];
    #pragma unroll
    for (int off = 32; off; off >>= 1) acc += __shfl_xor(acc, off);
    if (lane == 0) {
        float c = fmaxf((float)(end - beg), 1.0f);
        float v = acc / c;
        out[g] = 1.0f / (1.0f + expf(-v));
    }
}

extern "C" void kernel_launch(void* const* d_in, const int* in_sizes, int n_in,
                              void* d_out, int out_size, void* d_ws, size_t ws_size,
                              hipStream_t stream) {
    const float* x    = (const float*)d_in[0];
    const int*   eidx = (const int*)d_in[1];
    const int*   batch= (const int*)d_in[2];
    const float* W1 = (const float*)d_in[3];
    const float* b1 = (const float*)d_in[4];
    const float* W2 = (const float*)d_in[5];
    const float* b2 = (const float*)d_in[6];
    const float* W3 = (const float*)d_in[7];
    const float* b3 = (const float*)d_in[8];
    const float* W4 = (const float*)d_in[9];
    const float* b4 = (const float*)d_in[10];

    const int n  = in_sizes[0] / 6;
    const int e  = in_sizes[1] / 2;
    const int ng = out_size;
    const int* src = eidx;
    const int* dst = eidx + e;
    const int nbuk = (n + BKT - 1) / BKT;   // 1563 @ n=100k (MAXBUK cap)

    // workspace layout
    char* ws = (char*)d_ws;
    float* bufA   = (float*)ws; ws += (size_t)n * 128 * 4;   // xs / CSR scratch / hb
    void*  gbuf   = (void*)ws;  ws += (size_t)n * 128 * 4;   // ax / sliced fp8 gout
    int*   colarr = (int*)ws;   ws += (size_t)e * 4;
    int*   rowptr = (int*)ws;   ws += ((size_t)n + 4) * 4;
    float* dinv   = (float*)ws; ws += (size_t)n * 4;
    float* t      = (float*)ws; ws += (size_t)n * 4;
    float* sv     = (float*)ws; ws += (size_t)n * 4;
    unsigned short* wtg2 = (unsigned short*)ws; ws += 128 * WTP * 2;
    unsigned short* wtg3 = (unsigned short*)ws; ws += 128 * WTP * 2;

    // CSR-build scratch in bufA's tail (dead before gemm1 writes hb there)
    char* tail = (char*)bufA;
    int* part    = (int*)(tail + (16u << 20));   // e ints (6.4MB)
    int* hmatT   = (int*)(tail + (24u << 20));   // nbuk*NCH ints (800KB)
    int* totals  = (int*)(tail + (26u << 20));   // nbuk ints
    int* bukBase = (int*)(tail + (27u << 20));   // nbuk+1 ints

    float* xs = bufA;                       // [n,6] prescaled x
    float* ax = (float*)gbuf;               // [n,6] aggregated
    unsigned short* hb = (unsigned short*)bufA;  // [n,128] bf16 h

    const int nb = (n + 255) / 256;
    const int nw = (n + 3) / 4;
    const int gb = (n + MB - 1) / MB;

    // ---- CSR build (no device-scope atomics) + fused weight prep ----
    hist_wconv<<<NCH + 128, 256, 0, stream>>>(dst, hmatT, e, nbuk, W2, wtg2, W3, wtg3);
    scan_chunks<<<(nbuk + 3) / 4, 256, 0, stream>>>(hmatT, totals, nbuk);
    scan_kernel<<<1, 1024, 0, stream>>>(totals, bukBase, nbuk);
    partition_kernel<<<NCH, 256, 0, stream>>>(src, dst, hmatT, bukBase, part, e, nbuk);
    bucket_csr<<<nbuk, 256, 0, stream>>>(part, bukBase, colarr, rowptr, dinv, x, xs, n, e);

    // ---- layer 1: aggregate (6-dim) then GEMM -> bf16 h ----
    aggx_kernel<<<nb, 256, 0, stream>>>(xs, rowptr, colarr, dinv, ax, n);
    gemm1_kernel<<<(n * 128 + 255) / 256, 256, 0, stream>>>(ax, W1, b1, hb, n);

    // ---- layer 2 ----
    gemm128_mfma<<<gb, 256, 0, stream>>>(hb, wtg2, dinv, (int*)gbuf, n);
    for (int s = 0; s < 4; ++s)
        agg128_slice<<<nw, 256, 0, stream>>>((const int*)gbuf, rowptr, colarr, dinv, b2, hb, n, 1, s);

    // ---- layer 3 ----
    gemm128_mfma<<<gb, 256, 0, stream>>>(hb, wtg3, dinv, (int*)gbuf, n);
    for (int s = 0; s < 4; ++s)
        agg128_slice<<<nw, 256, 0, stream>>>((const int*)gbuf, rowptr, colarr, dinv, b3, hb, n, 1, s);

    // ---- layer 4: project to scalar, aggregate ----
    head_kernel<<<nw, 256, 0, stream>>>(hb, W4, dinv, t, n);
    aggs_kernel<<<nb, 256, 0, stream>>>(t, rowptr, colarr, dinv, b4, sv, n);

    // ---- pool: per-graph binary search on sorted batch + wave mean ----
    pool_kernel<<<(ng + 3) / 4, 256, 0, stream>>>(sv, batch, (float*)d_out, n, ng);
}

// Round 17
// 242.621 us; speedup vs baseline: 1.8729x; 1.8729x over previous
//
#include <hip/hip_runtime.h>
#include <math.h>

// ---------------------------------------------------------------------------
// SimpleGNN (4-layer GCN + mean pool + sigmoid) on MI355X.
//   - CSR build: atomic-free bucket sort (R6), NCH=128.
//   - R15 consolidation kept (hist+wconv fused, xscale in bucket_csr,
//     binary-search pool).
//   - R16 slicing REVERTED (regressed: compulsory per-XCD L3 fetches +
//     narrower rows; full-row agg128 @ ~50us is the gather wall).
//   - R17: gemm1 grid-stride (W1 staged once per block; was 50k blocks x
//     3.5KB staging for 1536 FMAs = 44us). head fused into layer-3 agg128
//     epilogue (dot with W4 instead of hb write).
//   - h in BF16; layers 2,3 = bf16 MFMA GEMM (16x16x32, MB=128) -> FP8
//     gather buffer; agg128 = R12 structure (2 edges/wave x dword, 4-gather
//     unroll, masked 8-edge tail).
// ---------------------------------------------------------------------------

typedef float f32x2 __attribute__((ext_vector_type(2)));
typedef float f32x4 __attribute__((ext_vector_type(4)));
typedef short bf16x8 __attribute__((ext_vector_type(8)));   // 8 bf16 = 4 VGPRs

#define BKT    64     // nodes per bucket (shift 6)
#define NCH    128    // edge chunks
#define MAXBUK 2048   // LDS bucket counters (nbuk = 1563 @ n=100k)
#define DCAP   2048   // per-bucket LDS colarr staging
#define WTP    136    // padded row length of transposed W (bf16)

// round-to-nearest-even f32 -> bf16
__device__ __forceinline__ unsigned short f2bf(float f) {
    unsigned u = __float_as_uint(f);
    return (unsigned short)((u + 0x7fffu + ((u >> 16) & 1u)) >> 16);
}
__device__ __forceinline__ float bf2f(unsigned short b) {
    return __uint_as_float((unsigned)b << 16);
}

// ---- CSR pass A + weight prep fused: blocks [0,NCH) hist, [NCH,NCH+128) wconv ----
__global__ __launch_bounds__(256) void hist_wconv(const int* __restrict__ dst,
                                                  int* __restrict__ hmatT,
                                                  int e, int nbuk,
                                                  const float* __restrict__ W2,
                                                  unsigned short* __restrict__ wtg2,
                                                  const float* __restrict__ W3,
                                                  unsigned short* __restrict__ wtg3) {
    if (blockIdx.x >= NCH) {
        int gid = (blockIdx.x - NCH) * 256 + threadIdx.x;   // [0, 32768)
        const float* W = (gid < 128 * 128) ? W2 : W3;
        unsigned short* wtg = (gid < 128 * 128) ? wtg2 : wtg3;
        int idx = gid & (128 * 128 - 1);
        int k = idx >> 7, c = idx & 127;
        wtg[c * WTP + k] = f2bf(W[idx]);
        return;
    }
    __shared__ int h[MAXBUK];
    for (int i = threadIdx.x; i < nbuk; i += 256) h[i] = 0;
    __syncthreads();
    const int per = (e + NCH - 1) / NCH;
    const int beg = blockIdx.x * per;
    const int end = min(beg + per, e);
    for (int i = beg + threadIdx.x; i < end; i += 256)
        atomicAdd(&h[dst[i] >> 6], 1);          // LDS atomic
    __syncthreads();
    for (int b = threadIdx.x; b < nbuk; b += 256)
        hmatT[b * NCH + blockIdx.x] = h[b];
}

// ---- CSR pass B1: per-bucket exclusive scan over its NCH chunk-counts ----
__global__ __launch_bounds__(256) void scan_chunks(int* __restrict__ hmatT,
                                                   int* __restrict__ totals, int nbuk) {
    int b = blockIdx.x * 4 + (threadIdx.x >> 6);
    if (b >= nbuk) return;
    const int lane = threadIdx.x & 63;
    int* row = hmatT + b * NCH;
    int carry = 0;
    #pragma unroll
    for (int q = 0; q < NCH / 64; ++q) {
        int v = row[q * 64 + lane];
        int x = v;
        #pragma unroll
        for (int off = 1; off < 64; off <<= 1) {
            int y = __shfl_up(x, off);
            if (lane >= off) x += y;
        }
        row[q * 64 + lane] = x - v + carry;
        carry += __shfl(x, 63);
    }
    if (lane == 0) totals[b] = carry;
}

// ---- CSR pass B2: single-block chunked exclusive scan ----
__global__ void scan_kernel(const int* __restrict__ counts, int* __restrict__ rowptr, int n) {
    __shared__ int wsum[16];
    __shared__ int carry_s;
    const int tid  = threadIdx.x;            // 1024 threads
    const int lane = tid & 63, wid = tid >> 6;
    if (tid == 0) carry_s = 0;
    __syncthreads();
    const int nchunk = (n + 4095) >> 12;
    for (int c = 0; c < nchunk; ++c) {
        int i0 = (c << 12) + tid * 4;
        int4 v = make_int4(0, 0, 0, 0);
        if (i0 + 3 < n) {
            v = *(const int4*)(counts + i0);
        } else {
            if (i0     < n) v.x = counts[i0];
            if (i0 + 1 < n) v.y = counts[i0 + 1];
            if (i0 + 2 < n) v.z = counts[i0 + 2];
            if (i0 + 3 < n) v.w = counts[i0 + 3];
        }
        int s1 = v.x, s2 = s1 + v.y, s3 = s2 + v.z, s4 = s3 + v.w;
        int x = s4;
        #pragma unroll
        for (int off = 1; off < 64; off <<= 1) {
            int y = __shfl_up(x, off);
            if (lane >= off) x += y;
        }
        if (lane == 63) wsum[wid] = x;
        __syncthreads();
        if (wid == 0) {
            int s = (lane < 16) ? wsum[lane] : 0;
            #pragma unroll
            for (int off = 1; off < 16; off <<= 1) {
                int y = __shfl_up(s, off);
                if (lane >= off) s += y;
            }
            if (lane < 16) wsum[lane] = s;
        }
        __syncthreads();
        int carry = carry_s + ((wid > 0) ? wsum[wid - 1] : 0);
        int excl  = carry + x - s4;
        if (i0     < n) rowptr[i0 + 1] = excl + s1;
        if (i0 + 1 < n) rowptr[i0 + 2] = excl + s2;
        if (i0 + 2 < n) rowptr[i0 + 3] = excl + s3;
        if (i0 + 3 < n) rowptr[i0 + 4] = excl + s4;
        __syncthreads();
        if (tid == 1023) carry_s = carry + x;
        __syncthreads();
    }
    if (tid == 0) rowptr[0] = 0;
}

// ---- CSR pass C: partition edges into bucket-grouped order ----
__global__ __launch_bounds__(256) void partition_kernel(const int* __restrict__ src,
                                                        const int* __restrict__ dst,
                                                        const int* __restrict__ hmatT,
                                                        const int* __restrict__ bukBase,
                                                        int* __restrict__ part,
                                                        int e, int nbuk) {
    __shared__ int cur[MAXBUK];
    for (int b = threadIdx.x; b < nbuk; b += 256)
        cur[b] = bukBase[b] + hmatT[b * NCH + blockIdx.x];
    __syncthreads();
    const int per = (e + NCH - 1) / NCH;
    const int beg = blockIdx.x * per;
    const int end = min(beg + per, e);
    for (int i = beg + threadIdx.x; i < end; i += 256) {
        int d = dst[i], s = src[i];
        int pos = atomicAdd(&cur[d >> 6], 1);   // LDS atomic
        part[pos] = (d & 63) | (s << 6);        // s < 2^17 -> fits
    }
}

// ---- CSR pass D: per-bucket local CSR finish + fused dinv + fused xscale ----
__global__ __launch_bounds__(256) void bucket_csr(const int* __restrict__ part,
                                                  const int* __restrict__ bukBase,
                                                  int* __restrict__ colarr,
                                                  int* __restrict__ rowptr,
                                                  float* __restrict__ dinv,
                                                  const float* __restrict__ x,
                                                  float* __restrict__ xs,
                                                  int n, int e) {
    __shared__ int hist[BKT];
    __shared__ int cursor[BKT];
    __shared__ float dls[BKT];
    __shared__ int loc[DCAP];
    const int b = blockIdx.x;
    const int ebeg = bukBase[b], eend = bukBase[b + 1];
    if (threadIdx.x < BKT) hist[threadIdx.x] = 0;
    __syncthreads();
    for (int i = ebeg + threadIdx.x; i < eend; i += 256)
        atomicAdd(&hist[part[i] & (BKT - 1)], 1);
    __syncthreads();
    if (threadIdx.x < 64) {
        const int lane = threadIdx.x;
        int c = hist[lane];
        int x0 = c;
        #pragma unroll
        for (int off = 1; off < 64; off <<= 1) { int y = __shfl_up(x0, off); if (lane >= off) x0 += y; }
        int excl = x0 - c;
        cursor[lane] = excl;
        float dv = rsqrtf((float)c + 1.0f);
        dls[lane] = dv;
        int node = b * BKT + lane;
        if (node < n) {
            rowptr[node] = ebeg + excl;
            dinv[node]   = dv;
        }
    }
    if (b == 0 && threadIdx.x == 0) rowptr[n] = e;
    __syncthreads();
    for (int i = ebeg + threadIdx.x; i < eend; i += 256) {
        int p = part[i];
        int pos = atomicAdd(&cursor[p & (BKT - 1)], 1);  // LDS atomic
        int s = p >> 6;
        if (pos < DCAP) loc[pos] = s;
        else colarr[ebeg + pos] = s;   // statistically unreachable overflow path
    }
    __syncthreads();
    const int cnt = min(eend - ebeg, DCAP);
    for (int i = threadIdx.x; i < cnt; i += 256) colarr[ebeg + i] = loc[i];
    // fused xscale: xs[node,c] = x[node,c] * dinv[node] for this bucket's nodes
    for (int i = threadIdx.x; i < BKT * 6; i += 256) {
        int node = b * BKT + i / 6;
        if (node < n) {
            int idx = node * 6 + (i % 6);
            xs[idx] = x[idx] * dls[i / 6];
        }
    }
}

// ax[i] = dinv[i] * ( sum_{s in N(i)} xs[s] + xs[i] )    (6-dim)
__global__ void aggx_kernel(const float* __restrict__ xs, const int* __restrict__ rowptr,
                            const int* __restrict__ colarr, const float* __restrict__ dinv,
                            float* __restrict__ ax, int n) {
    int i = blockIdx.x * 256 + threadIdx.x;
    if (i >= n) return;
    float a0 = 0, a1 = 0, a2 = 0, a3 = 0, a4 = 0, a5 = 0;
    int beg = rowptr[i], end = rowptr[i + 1];
    for (int e = beg; e < end; ++e) {
        int s = colarr[e];
        const float* xr = xs + (size_t)s * 6;
        a0 += xr[0]; a1 += xr[1]; a2 += xr[2];
        a3 += xr[3]; a4 += xr[4]; a5 += xr[5];
    }
    const float* xi = xs + (size_t)i * 6;
    float di = dinv[i];
    float* o = ax + (size_t)i * 6;
    o[0] = (a0 + xi[0]) * di;
    o[1] = (a1 + xi[1]) * di;
    o[2] = (a2 + xi[2]) * di;
    o[3] = (a3 + xi[3]) * di;
    o[4] = (a4 + xi[4]) * di;
    o[5] = (a5 + xi[5]) * di;
}

// h1 = bf16( relu(ax @ W1 + b1) )   (6 -> 128)
// R17: grid-stride (2048 blocks), W1 staged ONCE per block; 2 cols/thread,
// packed dword stores. (Was: 50k blocks x 3.5KB staging for 1536 FMAs.)
__global__ __launch_bounds__(256) void gemm1_kernel(const float* __restrict__ ax,
                                                    const float* __restrict__ W1,
                                                    const float* __restrict__ b1,
                                                    unsigned short* __restrict__ h1, int n) {
    __shared__ float Wl[6 * 128];
    __shared__ float bl[128];
    for (int i = threadIdx.x; i < 6 * 128; i += 256) Wl[i] = W1[i];
    if (threadIdx.x < 128) bl[threadIdx.x] = b1[threadIdx.x];
    __syncthreads();
    const int total = n * 64;                 // thread-task = (node, col-pair)
    unsigned int* h1p = (unsigned int*)h1;
    for (int gid = blockIdx.x * 256 + threadIdx.x; gid < total; gid += gridDim.x * 256) {
        int node = gid >> 6, c2 = (gid & 63) * 2;
        const float* ar = ax + (size_t)node * 6;
        float acc0 = bl[c2], acc1 = bl[c2 + 1];
        #pragma unroll
        for (int k = 0; k < 6; ++k) {
            float a = ar[k];
            acc0 += a * Wl[k * 128 + c2];
            acc1 += a * Wl[k * 128 + c2 + 1];
        }
        unsigned int w = (unsigned)f2bf(fmaxf(acc0, 0.f))
                       | ((unsigned)f2bf(fmaxf(acc1, 0.f)) << 16);
        h1p[(size_t)node * 64 + (gid & 63)] = w;
    }
}

// gout[node,:] = fp8( (hb[node,:] @ W) * dinv[node] )   via bf16 MFMA
// block = 256 threads = 4 waves; wave -> 2x16 nodes x 128 cols; K=128.
#define MB 128  // nodes per block (2 halves amortize Wt staging)
__global__ __launch_bounds__(256) void gemm128_mfma(const unsigned short* __restrict__ hb,
                                                    const unsigned short* __restrict__ wtg,
                                                    const float* __restrict__ dinv,
                                                    int* __restrict__ gout, int n) {
    __shared__ unsigned short Wt[128 * WTP];   // 34.8 KB, transposed W
    __shared__ float dl[MB];
    __shared__ float ctile[4][16][16];         // per-wave epilogue repack
    const int tid = threadIdx.x;
    const int node0 = blockIdx.x * MB;
    {   // stage Wt: straight 16B copies (wtg already transposed+padded)
        const int4* s4 = (const int4*)wtg;
        int4* d4 = (int4*)Wt;
        for (int i = tid; i < 128 * WTP * 2 / 16; i += 256) d4[i] = s4[i];
    }
    if (tid < MB) {
        int node = node0 + tid;
        dl[tid] = (node < n) ? dinv[node] : 0.f;
    }
    __syncthreads();
    const int wid  = tid >> 6, lane = tid & 63;
    const int ccol = lane & 15;
    const int koff = (lane >> 4) * 8;           // k-chunk within 32
    float* ct = &ctile[wid][0][0];
    #pragma unroll
    for (int half = 0; half < 2; ++half) {
        const int wn0  = node0 + half * 64 + wid * 16;   // this wave's 16 nodes
        const int arow = wn0 + (lane & 15);              // A row (hb has slack)
        bf16x8 a0 = *(const bf16x8*)(hb + (size_t)arow * 128 +  0 + koff);
        bf16x8 a1 = *(const bf16x8*)(hb + (size_t)arow * 128 + 32 + koff);
        bf16x8 a2 = *(const bf16x8*)(hb + (size_t)arow * 128 + 64 + koff);
        bf16x8 a3 = *(const bf16x8*)(hb + (size_t)arow * 128 + 96 + koff);
        #pragma unroll
        for (int nt = 0; nt < 8; ++nt) {            // 16-col output tiles
            const unsigned short* wb = Wt + (size_t)(nt * 16 + (lane & 15)) * WTP + koff;
            f32x4 c = {0.f, 0.f, 0.f, 0.f};
            c = __builtin_amdgcn_mfma_f32_16x16x32_bf16(a0, *(const bf16x8*)(wb +  0), c, 0, 0, 0);
            c = __builtin_amdgcn_mfma_f32_16x16x32_bf16(a1, *(const bf16x8*)(wb + 32), c, 0, 0, 0);
            c = __builtin_amdgcn_mfma_f32_16x16x32_bf16(a2, *(const bf16x8*)(wb + 64), c, 0, 0, 0);
            c = __builtin_amdgcn_mfma_f32_16x16x32_bf16(a3, *(const bf16x8*)(wb + 96), c, 0, 0, 0);
            #pragma unroll
            for (int r = 0; r < 4; ++r) {
                int row = (lane >> 4) * 4 + r;
                ct[row * 16 + ccol] = c[r] * dl[half * 64 + wid * 16 + row];
            }
            int rrow = lane >> 2, rdw = lane & 3;
            f32x4 v = *(const f32x4*)&ct[rrow * 16 + rdw * 4];
            int w = __builtin_amdgcn_cvt_pk_fp8_f32(v[0], v[1], 0, false);
            w     = __builtin_amdgcn_cvt_pk_fp8_f32(v[2], v[3], w, true);
            int onode = wn0 + rrow;
            if (onode < n) gout[(size_t)onode * 32 + nt * 4 + rdw] = w;
        }
    }
}

// out[i] = bf16( relu_opt( dinv[i]*( sum_{s in N(i)} g[s] + g[i] ) + b ) )  (fp8 g)
// R12 structure. R17: optional fused head — when w4 != nullptr, instead of
// writing hb the epilogue computes t[node] = dot(relu(row), W4) * dinv[node].
__global__ __launch_bounds__(256) void agg128_kernel(const void* __restrict__ g,
                                                     const int* __restrict__ rowptr,
                                                     const int* __restrict__ colarr,
                                                     const float* __restrict__ dinv,
                                                     const float* __restrict__ bias,
                                                     unsigned short* __restrict__ out,
                                                     int n, int relu,
                                                     const float* __restrict__ w4,
                                                     float* __restrict__ t) {
    int node = blockIdx.x * 4 + (threadIdx.x >> 6);
    if (node >= n) return;
    const int lane = threadIdx.x & 63;
    const int half = lane >> 5;        // edge-in-pair
    const int c    = lane & 31;        // dword index within row
    const int* gi = (const int*)g;     // row s -> gi[s*32 + c]
    const int beg = rowptr[node], end = rowptr[node + 1];
    float ax = 0.f, ay = 0.f, az = 0.f, aw = 0.f;
    int e = beg;
    // main: 8 edges/iter, 4 gathers in flight, no guards
    for (; e + 8 <= end; e += 8) {
        int s0 = colarr[e     + half];
        int s1 = colarr[e + 2 + half];
        int s2 = colarr[e + 4 + half];
        int s3 = colarr[e + 6 + half];
        int w0 = gi[(size_t)s0 * 32 + c];
        int w1 = gi[(size_t)s1 * 32 + c];
        int w2 = gi[(size_t)s2 * 32 + c];
        int w3 = gi[(size_t)s3 * 32 + c];
        f32x2 l0 = __builtin_amdgcn_cvt_pk_f32_fp8(w0, false);
        f32x2 h0 = __builtin_amdgcn_cvt_pk_f32_fp8(w0, true);
        f32x2 l1 = __builtin_amdgcn_cvt_pk_f32_fp8(w1, false);
        f32x2 h1 = __builtin_amdgcn_cvt_pk_f32_fp8(w1, true);
        f32x2 l2 = __builtin_amdgcn_cvt_pk_f32_fp8(w2, false);
        f32x2 h2 = __builtin_amdgcn_cvt_pk_f32_fp8(w2, true);
        f32x2 l3 = __builtin_amdgcn_cvt_pk_f32_fp8(w3, false);
        f32x2 h3 = __builtin_amdgcn_cvt_pk_f32_fp8(w3, true);
        ax += (l0[0] + l1[0]) + (l2[0] + l3[0]);
        ay += (l0[1] + l1[1]) + (l2[1] + l3[1]);
        az += (h0[0] + h1[0]) + (h2[0] + h3[0]);
        aw += (h0[1] + h1[1]) + (h2[1] + h3[1]);
    }
    // tail: single masked 8-edge block (tail length < 8)
    if (e < end) {
        int i0 = e     + half;
        int i1 = e + 2 + half;
        int i2 = e + 4 + half;
        int i3 = e + 6 + half;
        bool m0 = i0 < end, m1 = i1 < end, m2 = i2 < end, m3 = i3 < end;
        int s0 = m0 ? colarr[i0] : node;    // node's row is always valid
        int s1 = m1 ? colarr[i1] : node;
        int s2 = m2 ? colarr[i2] : node;
        int s3 = m3 ? colarr[i3] : node;
        int w0 = gi[(size_t)s0 * 32 + c];
        int w1 = gi[(size_t)s1 * 32 + c];
        int w2 = gi[(size_t)s2 * 32 + c];
        int w3 = gi[(size_t)s3 * 32 + c];
        f32x2 l0 = __builtin_amdgcn_cvt_pk_f32_fp8(w0, false);
        f32x2 h0 = __builtin_amdgcn_cvt_pk_f32_fp8(w0, true);
        f32x2 l1 = __builtin_amdgcn_cvt_pk_f32_fp8(w1, false);
        f32x2 h1 = __builtin_amdgcn_cvt_pk_f32_fp8(w1, true);
        f32x2 l2 = __builtin_amdgcn_cvt_pk_f32_fp8(w2, false);
        f32x2 h2 = __builtin_amdgcn_cvt_pk_f32_fp8(w2, true);
        f32x2 l3 = __builtin_amdgcn_cvt_pk_f32_fp8(w3, false);
        f32x2 h3 = __builtin_amdgcn_cvt_pk_f32_fp8(w3, true);
        ax += (m0 ? l0[0] : 0.f) + (m1 ? l1[0] : 0.f) + (m2 ? l2[0] : 0.f) + (m3 ? l3[0] : 0.f);
        ay += (m0 ? l0[1] : 0.f) + (m1 ? l1[1] : 0.f) + (m2 ? l2[1] : 0.f) + (m3 ? l3[1] : 0.f);
        az += (m0 ? h0[0] : 0.f) + (m1 ? h1[0] : 0.f) + (m2 ? h2[0] : 0.f) + (m3 ? h3[0] : 0.f);
        aw += (m0 ? h0[1] : 0.f) + (m1 ? h1[1] : 0.f) + (m2 ? h2[1] : 0.f) + (m3 ? h3[1] : 0.f);
    }
    // cross-half reduce: combine the two edge-halves
    ax += __shfl_xor(ax, 32);
    ay += __shfl_xor(ay, 32);
    az += __shfl_xor(az, 32);
    aw += __shfl_xor(aw, 32);
    if (lane < 32) {
        int wsv = gi[(size_t)node * 32 + lane];
        f32x2 slo = __builtin_amdgcn_cvt_pk_f32_fp8(wsv, false);
        f32x2 shi = __builtin_amdgcn_cvt_pk_f32_fp8(wsv, true);
        float4 b = ((const float4*)bias)[lane];
        float di = dinv[node];
        float ox = (ax + slo[0]) * di + b.x;
        float oy = (ay + slo[1]) * di + b.y;
        float oz = (az + shi[0]) * di + b.z;
        float ow = (aw + shi[1]) * di + b.w;
        if (relu) {
            ox = fmaxf(ox, 0.f); oy = fmaxf(oy, 0.f);
            oz = fmaxf(oz, 0.f); ow = fmaxf(ow, 0.f);
        }
        if (w4) {
            // fused head: t[node] = dot(row, W4) * dinv
            float4 wv = ((const float4*)w4)[lane];
            float p = ox * wv.x + oy * wv.y + oz * wv.z + ow * wv.w;
            #pragma unroll
            for (int off = 16; off; off >>= 1) p += __shfl_xor(p, off);
            if (lane == 0) t[node] = p * di;
        } else {
            ushort4 o;
            o.x = f2bf(ox); o.y = f2bf(oy); o.z = f2bf(oz); o.w = f2bf(ow);
            ((ushort4*)(out + (size_t)node * 128))[lane] = o;
        }
    }
}

// s[i] = dinv[i]*( sum t[s] + t[i] ) + b4
__global__ void aggs_kernel(const float* __restrict__ t, const int* __restrict__ rowptr,
                            const int* __restrict__ colarr, const float* __restrict__ dinv,
                            const float* __restrict__ b4, float* __restrict__ s, int n) {
    int i = blockIdx.x * 256 + threadIdx.x;
    if (i >= n) return;
    float acc = 0.f;
    int beg = rowptr[i], end = rowptr[i + 1];
    int e = beg;
    for (; e + 3 < end; e += 4) {
        acc += (t[colarr[e]] + t[colarr[e + 1]]) + (t[colarr[e + 2]] + t[colarr[e + 3]]);
    }
    for (; e < end; ++e) acc += t[colarr[e]];
    s[i] = (acc + t[i]) * dinv[i] + b4[0];
}

// one wave per graph: binary-search the sorted batch for this graph's range,
// then mean + sigmoid straight to d_out.
__global__ void pool_kernel(const float* __restrict__ sv, const int* __restrict__ batch,
                            float* __restrict__ out, int n, int ng) {
    int g = blockIdx.x * 4 + (threadIdx.x >> 6);
    if (g >= ng) return;
    int lane = threadIdx.x & 63;
    int lo = 0, hi = n;
    while (lo < hi) { int mid = (lo + hi) >> 1; if (batch[mid] < g) lo = mid + 1; else hi = mid; }
    int beg = lo;
    hi = n;
    while (lo < hi) { int mid = (lo + hi) >> 1; if (batch[mid] < g + 1) lo = mid + 1; else hi = mid; }
    int end = lo;
    float acc = 0.f;
    for (int i = beg + lane; i < end; i += 64) acc += sv[i];
    #pragma unroll
    for (int off = 32; off; off >>= 1) acc += __shfl_xor(acc, off);
    if (lane == 0) {
        float c = fmaxf((float)(end - beg), 1.0f);
        float v = acc / c;
        out[g] = 1.0f / (1.0f + expf(-v));
    }
}

extern "C" void kernel_launch(void* const* d_in, const int* in_sizes, int n_in,
                              void* d_out, int out_size, void* d_ws, size_t ws_size,
                              hipStream_t stream) {
    const float* x    = (const float*)d_in[0];
    const int*   eidx = (const int*)d_in[1];
    const int*   batch= (const int*)d_in[2];
    const float* W1 = (const float*)d_in[3];
    const float* b1 = (const float*)d_in[4];
    const float* W2 = (const float*)d_in[5];
    const float* b2 = (const float*)d_in[6];
    const float* W3 = (const float*)d_in[7];
    const float* b3 = (const float*)d_in[8];
    const float* W4 = (const float*)d_in[9];
    const float* b4 = (const float*)d_in[10];

    const int n  = in_sizes[0] / 6;
    const int e  = in_sizes[1] / 2;
    const int ng = out_size;
    const int* src = eidx;
    const int* dst = eidx + e;
    const int nbuk = (n + BKT - 1) / BKT;   // 1563 @ n=100k (MAXBUK cap)

    // workspace layout
    char* ws = (char*)d_ws;
    float* bufA   = (float*)ws; ws += (size_t)n * 128 * 4;   // xs / CSR scratch / hb
    void*  gbuf   = (void*)ws;  ws += (size_t)n * 128 * 4;   // ax / fp8 gout
    int*   colarr = (int*)ws;   ws += (size_t)e * 4;
    int*   rowptr = (int*)ws;   ws += ((size_t)n + 4) * 4;
    float* dinv   = (float*)ws; ws += (size_t)n * 4;
    float* t      = (float*)ws; ws += (size_t)n * 4;
    float* sv     = (float*)ws; ws += (size_t)n * 4;
    unsigned short* wtg2 = (unsigned short*)ws; ws += 128 * WTP * 2;
    unsigned short* wtg3 = (unsigned short*)ws; ws += 128 * WTP * 2;

    // CSR-build scratch in bufA's tail (dead before gemm1 writes hb there)
    char* tail = (char*)bufA;
    int* part    = (int*)(tail + (16u << 20));   // e ints (6.4MB)
    int* hmatT   = (int*)(tail + (24u << 20));   // nbuk*NCH ints (800KB)
    int* totals  = (int*)(tail + (26u << 20));   // nbuk ints
    int* bukBase = (int*)(tail + (27u << 20));   // nbuk+1 ints

    float* xs = bufA;                       // [n,6] prescaled x
    float* ax = (float*)gbuf;               // [n,6] aggregated
    unsigned short* hb = (unsigned short*)bufA;  // [n,128] bf16 h

    const int nb = (n + 255) / 256;
    const int nw = (n + 3) / 4;
    const int gb = (n + MB - 1) / MB;

    // ---- CSR build (no device-scope atomics) + fused weight prep ----
    hist_wconv<<<NCH + 128, 256, 0, stream>>>(dst, hmatT, e, nbuk, W2, wtg2, W3, wtg3);
    scan_chunks<<<(nbuk + 3) / 4, 256, 0, stream>>>(hmatT, totals, nbuk);
    scan_kernel<<<1, 1024, 0, stream>>>(totals, bukBase, nbuk);
    partition_kernel<<<NCH, 256, 0, stream>>>(src, dst, hmatT, bukBase, part, e, nbuk);
    bucket_csr<<<nbuk, 256, 0, stream>>>(part, bukBase, colarr, rowptr, dinv, x, xs, n, e);

    // ---- layer 1: aggregate (6-dim) then GEMM -> bf16 h ----
    aggx_kernel<<<nb, 256, 0, stream>>>(xs, rowptr, colarr, dinv, ax, n);
    gemm1_kernel<<<2048, 256, 0, stream>>>(ax, W1, b1, hb, n);

    // ---- layer 2 ----
    gemm128_mfma<<<gb, 256, 0, stream>>>(hb, wtg2, dinv, (int*)gbuf, n);
    agg128_kernel<<<nw, 256, 0, stream>>>(gbuf, rowptr, colarr, dinv, b2, hb, n, 1,
                                          nullptr, nullptr);

    // ---- layer 3 (+ fused head: writes t instead of hb) ----
    gemm128_mfma<<<gb, 256, 0, stream>>>(hb, wtg3, dinv, (int*)gbuf, n);
    agg128_kernel<<<nw, 256, 0, stream>>>(gbuf, rowptr, colarr, dinv, b3, hb, n, 1,
                                          W4, t);

    // ---- layer 4: aggregate scalars ----
    aggs_kernel<<<nb, 256, 0, stream>>>(t, rowptr, colarr, dinv, b4, sv, n);

    // ---- pool: per-graph binary search on sorted batch + wave mean ----
    pool_kernel<<<(ng + 3) / 4, 256, 0, stream>>>(sv, batch, (float*)d_out, n, ng);
}

// Round 18
// 237.701 us; speedup vs baseline: 1.9116x; 1.0207x over previous
//
#include <hip/hip_runtime.h>
#include <math.h>

// ---------------------------------------------------------------------------
// SimpleGNN (4-layer GCN + mean pool + sigmoid) on MI355X.
//   - CSR build: atomic-free bucket sort, NCH=128. R18: XCD-AFFINE CHUNK
//     SWIZZLE — chunk = (blk&7)*(NCH/8) + blk>>3 so adjacent per-chunk
//     windows in part[] are written by ONE XCD (R16 profile: partition wrote
//     31MB for a 6.4MB array = cross-XCD partial-line amplification).
//   - R15 consolidation (hist+wconv fused, xscale in bucket_csr, bsearch
//     pool); R17 gemm1 grid-stride + head fused into layer-3 agg epilogue.
//   - h in BF16; layers 2,3 = bf16 MFMA GEMM (16x16x32, MB=128) -> FP8
//     gather buffer; agg128 = R12 structure (frozen: ~50us gather wall).
// ---------------------------------------------------------------------------

typedef float f32x2 __attribute__((ext_vector_type(2)));
typedef float f32x4 __attribute__((ext_vector_type(4)));
typedef short bf16x8 __attribute__((ext_vector_type(8)));   // 8 bf16 = 4 VGPRs

#define BKT    64     // nodes per bucket (shift 6)
#define NCH    128    // edge chunks
#define MAXBUK 2048   // LDS bucket counters (nbuk = 1563 @ n=100k)
#define DCAP   2048   // per-bucket LDS colarr staging
#define WTP    136    // padded row length of transposed W (bf16)

// round-to-nearest-even f32 -> bf16
__device__ __forceinline__ unsigned short f2bf(float f) {
    unsigned u = __float_as_uint(f);
    return (unsigned short)((u + 0x7fffu + ((u >> 16) & 1u)) >> 16);
}
__device__ __forceinline__ float bf2f(unsigned short b) {
    return __uint_as_float((unsigned)b << 16);
}

// XCD-affine chunk id: blocks on XCD x handle contiguous chunks [x*16, x*16+16)
__device__ __forceinline__ int chunk_of(int blk) {
    return (blk & 7) * (NCH / 8) + (blk >> 3);
}

// ---- CSR pass A + weight prep fused: blocks [0,NCH) hist, [NCH,NCH+128) wconv ----
__global__ __launch_bounds__(256) void hist_wconv(const int* __restrict__ dst,
                                                  int* __restrict__ hmatT,
                                                  int e, int nbuk,
                                                  const float* __restrict__ W2,
                                                  unsigned short* __restrict__ wtg2,
                                                  const float* __restrict__ W3,
                                                  unsigned short* __restrict__ wtg3) {
    if (blockIdx.x >= NCH) {
        int gid = (blockIdx.x - NCH) * 256 + threadIdx.x;   // [0, 32768)
        const float* W = (gid < 128 * 128) ? W2 : W3;
        unsigned short* wtg = (gid < 128 * 128) ? wtg2 : wtg3;
        int idx = gid & (128 * 128 - 1);
        int k = idx >> 7, c = idx & 127;
        wtg[c * WTP + k] = f2bf(W[idx]);
        return;
    }
    const int chunk = chunk_of(blockIdx.x);
    __shared__ int h[MAXBUK];
    for (int i = threadIdx.x; i < nbuk; i += 256) h[i] = 0;
    __syncthreads();
    const int per = (e + NCH - 1) / NCH;
    const int beg = chunk * per;
    const int end = min(beg + per, e);
    for (int i = beg + threadIdx.x; i < end; i += 256)
        atomicAdd(&h[dst[i] >> 6], 1);          // LDS atomic
    __syncthreads();
    for (int b = threadIdx.x; b < nbuk; b += 256)
        hmatT[b * NCH + chunk] = h[b];
}

// ---- CSR pass B1: per-bucket exclusive scan over its NCH chunk-counts ----
__global__ __launch_bounds__(256) void scan_chunks(int* __restrict__ hmatT,
                                                   int* __restrict__ totals, int nbuk) {
    int b = blockIdx.x * 4 + (threadIdx.x >> 6);
    if (b >= nbuk) return;
    const int lane = threadIdx.x & 63;
    int* row = hmatT + b * NCH;
    int carry = 0;
    #pragma unroll
    for (int q = 0; q < NCH / 64; ++q) {
        int v = row[q * 64 + lane];
        int x = v;
        #pragma unroll
        for (int off = 1; off < 64; off <<= 1) {
            int y = __shfl_up(x, off);
            if (lane >= off) x += y;
        }
        row[q * 64 + lane] = x - v + carry;
        carry += __shfl(x, 63);
    }
    if (lane == 0) totals[b] = carry;
}

// ---- CSR pass B2: single-block chunked exclusive scan ----
__global__ void scan_kernel(const int* __restrict__ counts, int* __restrict__ rowptr, int n) {
    __shared__ int wsum[16];
    __shared__ int carry_s;
    const int tid  = threadIdx.x;            // 1024 threads
    const int lane = tid & 63, wid = tid >> 6;
    if (tid == 0) carry_s = 0;
    __syncthreads();
    const int nchunk = (n + 4095) >> 12;
    for (int c = 0; c < nchunk; ++c) {
        int i0 = (c << 12) + tid * 4;
        int4 v = make_int4(0, 0, 0, 0);
        if (i0 + 3 < n) {
            v = *(const int4*)(counts + i0);
        } else {
            if (i0     < n) v.x = counts[i0];
            if (i0 + 1 < n) v.y = counts[i0 + 1];
            if (i0 + 2 < n) v.z = counts[i0 + 2];
            if (i0 + 3 < n) v.w = counts[i0 + 3];
        }
        int s1 = v.x, s2 = s1 + v.y, s3 = s2 + v.z, s4 = s3 + v.w;
        int x = s4;
        #pragma unroll
        for (int off = 1; off < 64; off <<= 1) {
            int y = __shfl_up(x, off);
            if (lane >= off) x += y;
        }
        if (lane == 63) wsum[wid] = x;
        __syncthreads();
        if (wid == 0) {
            int s = (lane < 16) ? wsum[lane] : 0;
            #pragma unroll
            for (int off = 1; off < 16; off <<= 1) {
                int y = __shfl_up(s, off);
                if (lane >= off) s += y;
            }
            if (lane < 16) wsum[lane] = s;
        }
        __syncthreads();
        int carry = carry_s + ((wid > 0) ? wsum[wid - 1] : 0);
        int excl  = carry + x - s4;
        if (i0     < n) rowptr[i0 + 1] = excl + s1;
        if (i0 + 1 < n) rowptr[i0 + 2] = excl + s2;
        if (i0 + 2 < n) rowptr[i0 + 3] = excl + s3;
        if (i0 + 3 < n) rowptr[i0 + 4] = excl + s4;
        __syncthreads();
        if (tid == 1023) carry_s = carry + x;
        __syncthreads();
    }
    if (tid == 0) rowptr[0] = 0;
}

// ---- CSR pass C: partition edges into bucket-grouped order ----
__global__ __launch_bounds__(256) void partition_kernel(const int* __restrict__ src,
                                                        const int* __restrict__ dst,
                                                        const int* __restrict__ hmatT,
                                                        const int* __restrict__ bukBase,
                                                        int* __restrict__ part,
                                                        int e, int nbuk) {
    const int chunk = chunk_of(blockIdx.x);
    __shared__ int cur[MAXBUK];
    for (int b = threadIdx.x; b < nbuk; b += 256)
        cur[b] = bukBase[b] + hmatT[b * NCH + chunk];
    __syncthreads();
    const int per = (e + NCH - 1) / NCH;
    const int beg = chunk * per;
    const int end = min(beg + per, e);
    for (int i = beg + threadIdx.x; i < end; i += 256) {
        int d = dst[i], s = src[i];
        int pos = atomicAdd(&cur[d >> 6], 1);   // LDS atomic
        part[pos] = (d & 63) | (s << 6);        // s < 2^17 -> fits
    }
}

// ---- CSR pass D: per-bucket local CSR finish + fused dinv + fused xscale ----
__global__ __launch_bounds__(256) void bucket_csr(const int* __restrict__ part,
                                                  const int* __restrict__ bukBase,
                                                  int* __restrict__ colarr,
                                                  int* __restrict__ rowptr,
                                                  float* __restrict__ dinv,
                                                  const float* __restrict__ x,
                                                  float* __restrict__ xs,
                                                  int n, int e) {
    __shared__ int hist[BKT];
    __shared__ int cursor[BKT];
    __shared__ float dls[BKT];
    __shared__ int loc[DCAP];
    const int b = blockIdx.x;
    const int ebeg = bukBase[b], eend = bukBase[b + 1];
    if (threadIdx.x < BKT) hist[threadIdx.x] = 0;
    __syncthreads();
    for (int i = ebeg + threadIdx.x; i < eend; i += 256)
        atomicAdd(&hist[part[i] & (BKT - 1)], 1);
    __syncthreads();
    if (threadIdx.x < 64) {
        const int lane = threadIdx.x;
        int c = hist[lane];
        int x0 = c;
        #pragma unroll
        for (int off = 1; off < 64; off <<= 1) { int y = __shfl_up(x0, off); if (lane >= off) x0 += y; }
        int excl = x0 - c;
        cursor[lane] = excl;
        float dv = rsqrtf((float)c + 1.0f);
        dls[lane] = dv;
        int node = b * BKT + lane;
        if (node < n) {
            rowptr[node] = ebeg + excl;
            dinv[node]   = dv;
        }
    }
    if (b == 0 && threadIdx.x == 0) rowptr[n] = e;
    __syncthreads();
    for (int i = ebeg + threadIdx.x; i < eend; i += 256) {
        int p = part[i];
        int pos = atomicAdd(&cursor[p & (BKT - 1)], 1);  // LDS atomic
        int s = p >> 6;
        if (pos < DCAP) loc[pos] = s;
        else colarr[ebeg + pos] = s;   // statistically unreachable overflow path
    }
    __syncthreads();
    const int cnt = min(eend - ebeg, DCAP);
    for (int i = threadIdx.x; i < cnt; i += 256) colarr[ebeg + i] = loc[i];
    // fused xscale: xs[node,c] = x[node,c] * dinv[node] for this bucket's nodes
    for (int i = threadIdx.x; i < BKT * 6; i += 256) {
        int node = b * BKT + i / 6;
        if (node < n) {
            int idx = node * 6 + (i % 6);
            xs[idx] = x[idx] * dls[i / 6];
        }
    }
}

// ax[i] = dinv[i] * ( sum_{s in N(i)} xs[s] + xs[i] )    (6-dim)
__global__ void aggx_kernel(const float* __restrict__ xs, const int* __restrict__ rowptr,
                            const int* __restrict__ colarr, const float* __restrict__ dinv,
                            float* __restrict__ ax, int n) {
    int i = blockIdx.x * 256 + threadIdx.x;
    if (i >= n) return;
    float a0 = 0, a1 = 0, a2 = 0, a3 = 0, a4 = 0, a5 = 0;
    int beg = rowptr[i], end = rowptr[i + 1];
    for (int e = beg; e < end; ++e) {
        int s = colarr[e];
        const float* xr = xs + (size_t)s * 6;
        a0 += xr[0]; a1 += xr[1]; a2 += xr[2];
        a3 += xr[3]; a4 += xr[4]; a5 += xr[5];
    }
    const float* xi = xs + (size_t)i * 6;
    float di = dinv[i];
    float* o = ax + (size_t)i * 6;
    o[0] = (a0 + xi[0]) * di;
    o[1] = (a1 + xi[1]) * di;
    o[2] = (a2 + xi[2]) * di;
    o[3] = (a3 + xi[3]) * di;
    o[4] = (a4 + xi[4]) * di;
    o[5] = (a5 + xi[5]) * di;
}

// h1 = bf16( relu(ax @ W1 + b1) )   (6 -> 128)
// grid-stride (2048 blocks), W1 staged ONCE per block; 2 cols/thread.
__global__ __launch_bounds__(256) void gemm1_kernel(const float* __restrict__ ax,
                                                    const float* __restrict__ W1,
                                                    const float* __restrict__ b1,
                                                    unsigned short* __restrict__ h1, int n) {
    __shared__ float Wl[6 * 128];
    __shared__ float bl[128];
    for (int i = threadIdx.x; i < 6 * 128; i += 256) Wl[i] = W1[i];
    if (threadIdx.x < 128) bl[threadIdx.x] = b1[threadIdx.x];
    __syncthreads();
    const int total = n * 64;                 // thread-task = (node, col-pair)
    unsigned int* h1p = (unsigned int*)h1;
    for (int gid = blockIdx.x * 256 + threadIdx.x; gid < total; gid += gridDim.x * 256) {
        int node = gid >> 6, c2 = (gid & 63) * 2;
        const float* ar = ax + (size_t)node * 6;
        float acc0 = bl[c2], acc1 = bl[c2 + 1];
        #pragma unroll
        for (int k = 0; k < 6; ++k) {
            float a = ar[k];
            acc0 += a * Wl[k * 128 + c2];
            acc1 += a * Wl[k * 128 + c2 + 1];
        }
        unsigned int w = (unsigned)f2bf(fmaxf(acc0, 0.f))
                       | ((unsigned)f2bf(fmaxf(acc1, 0.f)) << 16);
        h1p[(size_t)node * 64 + (gid & 63)] = w;
    }
}

// gout[node,:] = fp8( (hb[node,:] @ W) * dinv[node] )   via bf16 MFMA
#define MB 128  // nodes per block (2 halves amortize Wt staging)
__global__ __launch_bounds__(256) void gemm128_mfma(const unsigned short* __restrict__ hb,
                                                    const unsigned short* __restrict__ wtg,
                                                    const float* __restrict__ dinv,
                                                    int* __restrict__ gout, int n) {
    __shared__ unsigned short Wt[128 * WTP];   // 34.8 KB, transposed W
    __shared__ float dl[MB];
    __shared__ float ctile[4][16][16];         // per-wave epilogue repack
    const int tid = threadIdx.x;
    const int node0 = blockIdx.x * MB;
    {   // stage Wt: straight 16B copies (wtg already transposed+padded)
        const int4* s4 = (const int4*)wtg;
        int4* d4 = (int4*)Wt;
        for (int i = tid; i < 128 * WTP * 2 / 16; i += 256) d4[i] = s4[i];
    }
    if (tid < MB) {
        int node = node0 + tid;
        dl[tid] = (node < n) ? dinv[node] : 0.f;
    }
    __syncthreads();
    const int wid  = tid >> 6, lane = tid & 63;
    const int ccol = lane & 15;
    const int koff = (lane >> 4) * 8;           // k-chunk within 32
    float* ct = &ctile[wid][0][0];
    #pragma unroll
    for (int half = 0; half < 2; ++half) {
        const int wn0  = node0 + half * 64 + wid * 16;   // this wave's 16 nodes
        const int arow = wn0 + (lane & 15);              // A row (hb has slack)
        bf16x8 a0 = *(const bf16x8*)(hb + (size_t)arow * 128 +  0 + koff);
        bf16x8 a1 = *(const bf16x8*)(hb + (size_t)arow * 128 + 32 + koff);
        bf16x8 a2 = *(const bf16x8*)(hb + (size_t)arow * 128 + 64 + koff);
        bf16x8 a3 = *(const bf16x8*)(hb + (size_t)arow * 128 + 96 + koff);
        #pragma unroll
        for (int nt = 0; nt < 8; ++nt) {            // 16-col output tiles
            const unsigned short* wb = Wt + (size_t)(nt * 16 + (lane & 15)) * WTP + koff;
            f32x4 c = {0.f, 0.f, 0.f, 0.f};
            c = __builtin_amdgcn_mfma_f32_16x16x32_bf16(a0, *(const bf16x8*)(wb +  0), c, 0, 0, 0);
            c = __builtin_amdgcn_mfma_f32_16x16x32_bf16(a1, *(const bf16x8*)(wb + 32), c, 0, 0, 0);
            c = __builtin_amdgcn_mfma_f32_16x16x32_bf16(a2, *(const bf16x8*)(wb + 64), c, 0, 0, 0);
            c = __builtin_amdgcn_mfma_f32_16x16x32_bf16(a3, *(const bf16x8*)(wb + 96), c, 0, 0, 0);
            #pragma unroll
            for (int r = 0; r < 4; ++r) {
                int row = (lane >> 4) * 4 + r;
                ct[row * 16 + ccol] = c[r] * dl[half * 64 + wid * 16 + row];
            }
            int rrow = lane >> 2, rdw = lane & 3;
            f32x4 v = *(const f32x4*)&ct[rrow * 16 + rdw * 4];
            int w = __builtin_amdgcn_cvt_pk_fp8_f32(v[0], v[1], 0, false);
            w     = __builtin_amdgcn_cvt_pk_fp8_f32(v[2], v[3], w, true);
            int onode = wn0 + rrow;
            if (onode < n) gout[(size_t)onode * 32 + nt * 4 + rdw] = w;
        }
    }
}

// out[i] = bf16( relu_opt( dinv[i]*( sum_{s in N(i)} g[s] + g[i] ) + b ) )  (fp8 g)
// R12 structure. Optional fused head (w4 != nullptr): t[node] = dot(row,W4)*dinv.
__global__ __launch_bounds__(256) void agg128_kernel(const void* __restrict__ g,
                                                     const int* __restrict__ rowptr,
                                                     const int* __restrict__ colarr,
                                                     const float* __restrict__ dinv,
                                                     const float* __restrict__ bias,
                                                     unsigned short* __restrict__ out,
                                                     int n, int relu,
                                                     const float* __restrict__ w4,
                                                     float* __restrict__ t) {
    int node = blockIdx.x * 4 + (threadIdx.x >> 6);
    if (node >= n) return;
    const int lane = threadIdx.x & 63;
    const int half = lane >> 5;        // edge-in-pair
    const int c    = lane & 31;        // dword index within row
    const int* gi = (const int*)g;     // row s -> gi[s*32 + c]
    const int beg = rowptr[node], end = rowptr[node + 1];
    float ax = 0.f, ay = 0.f, az = 0.f, aw = 0.f;
    int e = beg;
    // main: 8 edges/iter, 4 gathers in flight, no guards
    for (; e + 8 <= end; e += 8) {
        int s0 = colarr[e     + half];
        int s1 = colarr[e + 2 + half];
        int s2 = colarr[e + 4 + half];
        int s3 = colarr[e + 6 + half];
        int w0 = gi[(size_t)s0 * 32 + c];
        int w1 = gi[(size_t)s1 * 32 + c];
        int w2 = gi[(size_t)s2 * 32 + c];
        int w3 = gi[(size_t)s3 * 32 + c];
        f32x2 l0 = __builtin_amdgcn_cvt_pk_f32_fp8(w0, false);
        f32x2 h0 = __builtin_amdgcn_cvt_pk_f32_fp8(w0, true);
        f32x2 l1 = __builtin_amdgcn_cvt_pk_f32_fp8(w1, false);
        f32x2 h1 = __builtin_amdgcn_cvt_pk_f32_fp8(w1, true);
        f32x2 l2 = __builtin_amdgcn_cvt_pk_f32_fp8(w2, false);
        f32x2 h2 = __builtin_amdgcn_cvt_pk_f32_fp8(w2, true);
        f32x2 l3 = __builtin_amdgcn_cvt_pk_f32_fp8(w3, false);
        f32x2 h3 = __builtin_amdgcn_cvt_pk_f32_fp8(w3, true);
        ax += (l0[0] + l1[0]) + (l2[0] + l3[0]);
        ay += (l0[1] + l1[1]) + (l2[1] + l3[1]);
        az += (h0[0] + h1[0]) + (h2[0] + h3[0]);
        aw += (h0[1] + h1[1]) + (h2[1] + h3[1]);
    }
    // tail: single masked 8-edge block (tail length < 8)
    if (e < end) {
        int i0 = e     + half;
        int i1 = e + 2 + half;
        int i2 = e + 4 + half;
        int i3 = e + 6 + half;
        bool m0 = i0 < end, m1 = i1 < end, m2 = i2 < end, m3 = i3 < end;
        int s0 = m0 ? colarr[i0] : node;    // node's row is always valid
        int s1 = m1 ? colarr[i1] : node;
        int s2 = m2 ? colarr[i2] : node;
        int s3 = m3 ? colarr[i3] : node;
        int w0 = gi[(size_t)s0 * 32 + c];
        int w1 = gi[(size_t)s1 * 32 + c];
        int w2 = gi[(size_t)s2 * 32 + c];
        int w3 = gi[(size_t)s3 * 32 + c];
        f32x2 l0 = __builtin_amdgcn_cvt_pk_f32_fp8(w0, false);
        f32x2 h0 = __builtin_amdgcn_cvt_pk_f32_fp8(w0, true);
        f32x2 l1 = __builtin_amdgcn_cvt_pk_f32_fp8(w1, false);
        f32x2 h1 = __builtin_amdgcn_cvt_pk_f32_fp8(w1, true);
        f32x2 l2 = __builtin_amdgcn_cvt_pk_f32_fp8(w2, false);
        f32x2 h2 = __builtin_amdgcn_cvt_pk_f32_fp8(w2, true);
        f32x2 l3 = __builtin_amdgcn_cvt_pk_f32_fp8(w3, false);
        f32x2 h3 = __builtin_amdgcn_cvt_pk_f32_fp8(w3, true);
        ax += (m0 ? l0[0] : 0.f) + (m1 ? l1[0] : 0.f) + (m2 ? l2[0] : 0.f) + (m3 ? l3[0] : 0.f);
        ay += (m0 ? l0[1] : 0.f) + (m1 ? l1[1] : 0.f) + (m2 ? l2[1] : 0.f) + (m3 ? l3[1] : 0.f);
        az += (m0 ? h0[0] : 0.f) + (m1 ? h1[0] : 0.f) + (m2 ? h2[0] : 0.f) + (m3 ? h3[0] : 0.f);
        aw += (m0 ? h0[1] : 0.f) + (m1 ? h1[1] : 0.f) + (m2 ? h2[1] : 0.f) + (m3 ? h3[1] : 0.f);
    }
    // cross-half reduce: combine the two edge-halves
    ax += __shfl_xor(ax, 32);
    ay += __shfl_xor(ay, 32);
    az += __shfl_xor(az, 32);
    aw += __shfl_xor(aw, 32);
    if (lane < 32) {
        int wsv = gi[(size_t)node * 32 + lane];
        f32x2 slo = __builtin_amdgcn_cvt_pk_f32_fp8(wsv, false);
        f32x2 shi = __builtin_amdgcn_cvt_pk_f32_fp8(wsv, true);
        float4 b = ((const float4*)bias)[lane];
        float di = dinv[node];
        float ox = (ax + slo[0]) * di + b.x;
        float oy = (ay + slo[1]) * di + b.y;
        float oz = (az + shi[0]) * di + b.z;
        float ow = (aw + shi[1]) * di + b.w;
        if (relu) {
            ox = fmaxf(ox, 0.f); oy = fmaxf(oy, 0.f);
            oz = fmaxf(oz, 0.f); ow = fmaxf(ow, 0.f);
        }
        if (w4) {
            float4 wv = ((const float4*)w4)[lane];
            float p = ox * wv.x + oy * wv.y + oz * wv.z + ow * wv.w;
            #pragma unroll
            for (int off = 16; off; off >>= 1) p += __shfl_xor(p, off);
            if (lane == 0) t[node] = p * di;
        } else {
            ushort4 o;
            o.x = f2bf(ox); o.y = f2bf(oy); o.z = f2bf(oz); o.w = f2bf(ow);
            ((ushort4*)(out + (size_t)node * 128))[lane] = o;
        }
    }
}

// s[i] = dinv[i]*( sum t[s] + t[i] ) + b4
__global__ void aggs_kernel(const float* __restrict__ t, const int* __restrict__ rowptr,
                            const int* __restrict__ colarr, const float* __restrict__ dinv,
                            const float* __restrict__ b4, float* __restrict__ s, int n) {
    int i = blockIdx.x * 256 + threadIdx.x;
    if (i >= n) return;
    float acc = 0.f;
    int beg = rowptr[i], end = rowptr[i + 1];
    int e = beg;
    for (; e + 3 < end; e += 4) {
        acc += (t[colarr[e]] + t[colarr[e + 1]]) + (t[colarr[e + 2]] + t[colarr[e + 3]]);
    }
    for (; e < end; ++e) acc += t[colarr[e]];
    s[i] = (acc + t[i]) * dinv[i] + b4[0];
}

// one wave per graph: binary-search the sorted batch for this graph's range,
// then mean + sigmoid straight to d_out.
__global__ void pool_kernel(const float* __restrict__ sv, const int* __restrict__ batch,
                            float* __restrict__ out, int n, int ng) {
    int g = blockIdx.x * 4 + (threadIdx.x >> 6);
    if (g >= ng) return;
    int lane = threadIdx.x & 63;
    int lo = 0, hi = n;
    while (lo < hi) { int mid = (lo + hi) >> 1; if (batch[mid] < g) lo = mid + 1; else hi = mid; }
    int beg = lo;
    hi = n;
    while (lo < hi) { int mid = (lo + hi) >> 1; if (batch[mid] < g + 1) lo = mid + 1; else hi = mid; }
    int end = lo;
    float acc = 0.f;
    for (int i = beg + lane; i < end; i += 64) acc += sv[i];
    #pragma unroll
    for (int off = 32; off; off >>= 1) acc += __shfl_xor(acc, off);
    if (lane == 0) {
        float c = fmaxf((float)(end - beg), 1.0f);
        float v = acc / c;
        out[g] = 1.0f / (1.0f + expf(-v));
    }
}

extern "C" void kernel_launch(void* const* d_in, const int* in_sizes, int n_in,
                              void* d_out, int out_size, void* d_ws, size_t ws_size,
                              hipStream_t stream) {
    const float* x    = (const float*)d_in[0];
    const int*   eidx = (const int*)d_in[1];
    const int*   batch= (const int*)d_in[2];
    const float* W1 = (const float*)d_in[3];
    const float* b1 = (const float*)d_in[4];
    const float* W2 = (const float*)d_in[5];
    const float* b2 = (const float*)d_in[6];
    const float* W3 = (const float*)d_in[7];
    const float* b3 = (const float*)d_in[8];
    const float* W4 = (const float*)d_in[9];
    const float* b4 = (const float*)d_in[10];

    const int n  = in_sizes[0] / 6;
    const int e  = in_sizes[1] / 2;
    const int ng = out_size;
    const int* src = eidx;
    const int* dst = eidx + e;
    const int nbuk = (n + BKT - 1) / BKT;   // 1563 @ n=100k (MAXBUK cap)

    // workspace layout
    char* ws = (char*)d_ws;
    float* bufA   = (float*)ws; ws += (size_t)n * 128 * 4;   // xs / CSR scratch / hb
    void*  gbuf   = (void*)ws;  ws += (size_t)n * 128 * 4;   // ax / fp8 gout
    int*   colarr = (int*)ws;   ws += (size_t)e * 4;
    int*   rowptr = (int*)ws;   ws += ((size_t)n + 4) * 4;
    float* dinv   = (float*)ws; ws += (size_t)n * 4;
    float* t      = (float*)ws; ws += (size_t)n * 4;
    float* sv     = (float*)ws; ws += (size_t)n * 4;
    unsigned short* wtg2 = (unsigned short*)ws; ws += 128 * WTP * 2;
    unsigned short* wtg3 = (unsigned short*)ws; ws += 128 * WTP * 2;

    // CSR-build scratch in bufA's tail (dead before gemm1 writes hb there)
    char* tail = (char*)bufA;
    int* part    = (int*)(tail + (16u << 20));   // e ints (6.4MB)
    int* hmatT   = (int*)(tail + (24u << 20));   // nbuk*NCH ints (800KB)
    int* totals  = (int*)(tail + (26u << 20));   // nbuk ints
    int* bukBase = (int*)(tail + (27u << 20));   // nbuk+1 ints

    float* xs = bufA;                       // [n,6] prescaled x
    float* ax = (float*)gbuf;               // [n,6] aggregated
    unsigned short* hb = (unsigned short*)bufA;  // [n,128] bf16 h

    const int nb = (n + 255) / 256;
    const int nw = (n + 3) / 4;
    const int gb = (n + MB - 1) / MB;

    // ---- CSR build (no device-scope atomics) + fused weight prep ----
    hist_wconv<<<NCH + 128, 256, 0, stream>>>(dst, hmatT, e, nbuk, W2, wtg2, W3, wtg3);
    scan_chunks<<<(nbuk + 3) / 4, 256, 0, stream>>>(hmatT, totals, nbuk);
    scan_kernel<<<1, 1024, 0, stream>>>(totals, bukBase, nbuk);
    partition_kernel<<<NCH, 256, 0, stream>>>(src, dst, hmatT, bukBase, part, e, nbuk);
    bucket_csr<<<nbuk, 256, 0, stream>>>(part, bukBase, colarr, rowptr, dinv, x, xs, n, e);

    // ---- layer 1: aggregate (6-dim) then GEMM -> bf16 h ----
    aggx_kernel<<<nb, 256, 0, stream>>>(xs, rowptr, colarr, dinv, ax, n);
    gemm1_kernel<<<2048, 256, 0, stream>>>(ax, W1, b1, hb, n);

    // ---- layer 2 ----
    gemm128_mfma<<<gb, 256, 0, stream>>>(hb, wtg2, dinv, (int*)gbuf, n);
    agg128_kernel<<<nw, 256, 0, stream>>>(gbuf, rowptr, colarr, dinv, b2, hb, n, 1,
                                          nullptr, nullptr);

    // ---- layer 3 (+ fused head: writes t instead of hb) ----
    gemm128_mfma<<<gb, 256, 0, stream>>>(hb, wtg3, dinv, (int*)gbuf, n);
    agg128_kernel<<<nw, 256, 0, stream>>>(gbuf, rowptr, colarr, dinv, b3, hb, n, 1,
                                          W4, t);

    // ---- layer 4: aggregate scalars ----
    aggs_kernel<<<nb, 256, 0, stream>>>(t, rowptr, colarr, dinv, b4, sv, n);

    // ---- pool: per-graph binary search on sorted batch + wave mean ----
    pool_kernel<<<(ng + 3) / 4, 256, 0, stream>>>(sv, batch, (float*)d_out, n, ng);
}